// Round 7
// baseline (306.701 us; speedup 1.0000x reference)
//
#include <hip/hip_runtime.h>
#include <cstddef>

#define NSEQ   1025
#define NBATCH 8
#define NTOK   8200      // 8*1025
#define DIMX   768
#define NHEADS 12
#define DHEAD  64
#define VTP    1040      // Vt row pitch (bf16), 16B-aligned
#define LDP    72        // Ps row pitch (bf16)
#define CP     136       // epilogue repack pitch (bf16)

typedef short bf16x8 __attribute__((ext_vector_type(8)));
typedef float f32x4  __attribute__((ext_vector_type(4)));
typedef unsigned short u16;

__device__ __forceinline__ float bf2f(u16 u) {
    unsigned v = (unsigned)u << 16; float f; __builtin_memcpy(&f, &v, 4); return f;
}
__device__ __forceinline__ u16 f2bf(float f) {
    unsigned u; __builtin_memcpy(&u, &f, 4);
    return (u16)((u + 0x7FFFu + ((u >> 16) & 1u)) >> 16);   // RNE
}

// async 16B global->LDS (dest = wave-uniform base + lane*16)
__device__ __forceinline__ void gl2lds16(const u16* g, u16* l) {
    __builtin_amdgcn_global_load_lds((__attribute__((address_space(1))) void*)g,
                                     (__attribute__((address_space(3))) void*)l, 16, 0, 0);
}

// ---------------- LayerNorm (+ fused cls->q scatter, q pre-scaled 1/8) ----------------
__launch_bounds__(256)
__global__ void ln_kernel(const float* __restrict__ x, const float* __restrict__ g,
                          const float* __restrict__ bb, u16* __restrict__ xn,
                          u16* __restrict__ qout)
{
    int t = blockIdx.x, tid = threadIdx.x;
    const float* xp = x + (size_t)t * DIMX;
    float v0 = xp[tid], v1 = xp[tid + 256], v2 = xp[tid + 512];
    float s  = v0 + v1 + v2;
    float ss = v0*v0 + v1*v1 + v2*v2;
    for (int off = 32; off > 0; off >>= 1) {
        s  += __shfl_down(s,  off, 64);
        ss += __shfl_down(ss, off, 64);
    }
    __shared__ float red[8];
    __shared__ float stats[2];
    int w = tid >> 6, lane = tid & 63;
    if (lane == 0) { red[w] = s; red[4 + w] = ss; }
    __syncthreads();
    if (tid == 0) {
        float S  = red[0] + red[1] + red[2] + red[3];
        float SS = red[4] + red[5] + red[6] + red[7];
        float mu  = S * (1.0f / DIMX);
        float var = SS * (1.0f / DIMX) - mu * mu;
        stats[0] = mu; stats[1] = rsqrtf(var + 1e-5f);
    }
    __syncthreads();
    float mu = stats[0], rs = stats[1];
    float y0 = (v0 - mu) * rs * g[tid]       + bb[tid];
    float y1 = (v1 - mu) * rs * g[tid + 256] + bb[tid + 256];
    float y2 = (v2 - mu) * rs * g[tid + 512] + bb[tid + 512];
    u16* op = xn + (size_t)t * DIMX;
    op[tid] = f2bf(y0); op[tid + 256] = f2bf(y1); op[tid + 512] = f2bf(y2);
    int bq = t / NSEQ;
    if (t == bq * NSEQ) {   // cls token -> q row 0, head layout, pre-scaled by 1/8
        int c0 = tid, c1 = tid + 256, c2 = tid + 512;
        qout[((size_t)(bq * NHEADS + (c0 >> 6)) * NSEQ) * DHEAD + (c0 & 63)] = f2bf(y0 * 0.125f);
        qout[((size_t)(bq * NHEADS + (c1 >> 6)) * NSEQ) * DHEAD + (c1 & 63)] = f2bf(y1 * 0.125f);
        qout[((size_t)(bq * NHEADS + (c2 >> 6)) * NSEQ) * DHEAD + (c2 & 63)] = f2bf(y2 * 0.125f);
    }
}

// ---------------- fused weight preprocessing ----------------
__launch_bounds__(256)
__global__ void preproc_kernel(const float* __restrict__ dw_w, const float* __restrict__ pw_w,
                               const float* __restrict__ kv_w, const float* __restrict__ out_w,
                               float* __restrict__ dwT, u16* __restrict__ pw_bf,
                               u16* __restrict__ kv_wT, u16* __restrict__ out_wT)
{
    __shared__ float tile[32][33];
    int blk = blockIdx.x, tid = threadIdx.x;
    if (blk < 75) {
        int idx = blk * 256 + tid;
        if (idx < 768 * 25) {
            int c = idx / 25, wi = idx % 25;
            dwT[wi * 768 + c] = dw_w[idx];
        }
        return;
    }
    if (blk < 2379) {
        int i = (blk - 75) * 256 + tid;
        pw_bf[i] = f2bf(pw_w[i]);
        return;
    }
    const float* in; u16* out; int R, C, bx, by;
    if (blk < 3531) {
        int t2 = blk - 2379; bx = t2 % 48; by = t2 / 48;
        in = kv_w; out = kv_wT; R = 768; C = 1536;
    } else {
        int t2 = blk - 3531; bx = t2 % 24; by = t2 / 24;
        in = out_w; out = out_wT; R = 768; C = 768;
    }
    int tx = tid & 31, ty = tid >> 5;
    int xg = bx * 32 + tx, y0 = by * 32;
    for (int i = ty; i < 32; i += 8)
        tile[i][tx] = in[(size_t)(y0 + i) * C + xg];
    __syncthreads();
    int xo = by * 32 + tx, yo0 = bx * 32;
    for (int i = ty; i < 32; i += 8)
        out[(size_t)(yo0 + i) * R + xo] = f2bf(tile[tx][i]);
}

// ---------------- depthwise 5x5 conv, vectorized: 8 channels/thread ----------------
__launch_bounds__(256)
__global__ void dw_kernel(const u16* __restrict__ xn, const float* __restrict__ wt,
                          u16* __restrict__ out)
{
    int gid = blockIdx.x * 256 + threadIdx.x;      // 786432 = 8192 px * 96 groups
    int pix = gid / 96, cg = gid - pix * 96;
    int c = cg * 8;
    int b = pix >> 10, p = pix & 1023, y = p >> 5, x0 = p & 31;
    float acc[8] = {};
    for (int dy = 0; dy < 5; dy++) {
        int yy = y + dy - 2;
        if ((unsigned)yy >= 32u) continue;
        for (int dx = 0; dx < 5; dx++) {
            int xx = x0 + dx - 2;
            if ((unsigned)xx >= 32u) continue;
            const u16* ip = xn + ((size_t)(b * NSEQ) + 1 + yy * 32 + xx) * DIMX + c;
            uint4 iv = *(const uint4*)ip;
            const float* wp = wt + (dy * 5 + dx) * DIMX + c;
            float4 w0 = *(const float4*)wp;
            float4 w1 = *(const float4*)(wp + 4);
            acc[0] += bf2f((u16)(iv.x & 0xFFFFu)) * w0.x;
            acc[1] += bf2f((u16)(iv.x >> 16))     * w0.y;
            acc[2] += bf2f((u16)(iv.y & 0xFFFFu)) * w0.z;
            acc[3] += bf2f((u16)(iv.y >> 16))     * w0.w;
            acc[4] += bf2f((u16)(iv.z & 0xFFFFu)) * w1.x;
            acc[5] += bf2f((u16)(iv.z >> 16))     * w1.y;
            acc[6] += bf2f((u16)(iv.w & 0xFFFFu)) * w1.z;
            acc[7] += bf2f((u16)(iv.w >> 16))     * w1.w;
        }
    }
    uint4 ov;
    ov.x = (unsigned)f2bf(acc[0]) | ((unsigned)f2bf(acc[1]) << 16);
    ov.y = (unsigned)f2bf(acc[2]) | ((unsigned)f2bf(acc[3]) << 16);
    ov.z = (unsigned)f2bf(acc[4]) | ((unsigned)f2bf(acc[5]) << 16);
    ov.w = (unsigned)f2bf(acc[6]) | ((unsigned)f2bf(acc[7]) << 16);
    *(uint4*)(out + (size_t)pix * DIMX + c) = ov;
}

// ---------------- bf16 MFMA GEMM, async staging + fused rope/scale epilogues ----------
// MODE 0: kv -> K bf16 head-scatter + rope (cols<768) / V plain (cols>=768)
// MODE 1: pw -> q head-scatter (n=pix+1), scaled 1/8 + rope
// MODE 2: out -> fp32 d_out + bias
template<int MODE>
__launch_bounds__(256)
__global__ void gemm_bf16(const u16* __restrict__ A, const u16* __restrict__ Bn,
                          const float* __restrict__ bias, u16* __restrict__ Ob0,
                          u16* __restrict__ Ob1, float* __restrict__ Of,
                          const float* __restrict__ sinb, const float* __restrict__ cosb,
                          int M)
{
    __shared__ u16 smem[128 * CP];          // As(16KB)+Bs(16KB) then Ct repack
    u16* As = smem;
    u16* Bs = smem + 8192;
    const int tid  = threadIdx.x;
    const int wave = tid >> 6, lane = tid & 63;
    const int q8 = lane >> 4, cc = lane & 15;
    const int wr = wave >> 1, wc = wave & 1;
    const long r0 = (long)blockIdx.y * 128;
    const int  c0 = blockIdx.x * 128;

    f32x4 acc[4][4] = {};

    for (int k0 = 0; k0 < 768; k0 += 64) {
        __syncthreads();                    // prior iter's fragment reads done
        #pragma unroll
        for (int p = 0; p < 4; p++) {
            int chunk = wave * 256 + p * 64 + lane;      // 1024 chunks per 128x64 tile
            int row = chunk >> 3, cs = chunk & 7;
            int src = cs ^ (row & 7);                     // swizzled source chunk
            const u16* ga = A  + (size_t)(r0 + row) * 768 + k0 + src * 8;
            const u16* gb = Bn + (size_t)(c0 + row) * 768 + k0 + src * 8;
            u16* la = As + (size_t)(wave * 256 + p * 64) * 8;   // wave-uniform base
            u16* lb = Bs + (size_t)(wave * 256 + p * 64) * 8;
            gl2lds16(ga, la);
            gl2lds16(gb, lb);
        }
        __syncthreads();                    // drains vmcnt -> LDS valid
        #pragma unroll
        for (int ks = 0; ks < 2; ks++) {
            const int chsw = (((ks * 4 + q8) ^ (cc & 7)) * 8);
            bf16x8 af[4], bfr[4];
            #pragma unroll
            for (int mi = 0; mi < 4; mi++)
                af[mi] = *(const bf16x8*)(As + (wr * 64 + mi * 16 + cc) * 64 + chsw);
            #pragma unroll
            for (int ni = 0; ni < 4; ni++)
                bfr[ni] = *(const bf16x8*)(Bs + (wc * 64 + ni * 16 + cc) * 64 + chsw);
            #pragma unroll
            for (int mi = 0; mi < 4; mi++)
                #pragma unroll
                for (int ni = 0; ni < 4; ni++)
                    acc[mi][ni] = __builtin_amdgcn_mfma_f32_16x16x32_bf16(af[mi], bfr[ni], acc[mi][ni], 0, 0, 0);
        }
    }

    if (MODE == 2) {
        #pragma unroll
        for (int mi = 0; mi < 4; mi++) {
            #pragma unroll
            for (int r = 0; r < 4; r++) {
                long row = r0 + wr * 64 + mi * 16 + q8 * 4 + r;
                if (row >= M) continue;
                #pragma unroll
                for (int ni = 0; ni < 4; ni++) {
                    int col = c0 + wc * 64 + ni * 16 + cc;
                    Of[(size_t)row * 768 + col] = acc[mi][ni][r] + bias[col];
                }
            }
        }
        return;
    }

    // modes 0/1: repack through LDS, then coalesced 16B stores in head layout (+rope)
    __syncthreads();                        // all fragment reads done; reuse smem as Ct
    #pragma unroll
    for (int mi = 0; mi < 4; mi++)
        #pragma unroll
        for (int r = 0; r < 4; r++) {
            int lr = wr * 64 + mi * 16 + q8 * 4 + r;
            #pragma unroll
            for (int ni = 0; ni < 4; ni++)
                smem[lr * CP + wc * 64 + ni * 16 + cc] = f2bf(acc[mi][ni][r]);
        }
    __syncthreads();
    #pragma unroll
    for (int p = 0; p < 8; p++) {
        int id = p * 256 + tid;             // 2048 uint4 chunks (128 rows x 16)
        int row = id >> 4, c8 = (id & 15) * 8;
        long grow = r0 + row;
        if (grow >= M) continue;
        uint4 val = *(const uint4*)(smem + row * CP + c8);
        int b, n;
        if (MODE == 1) { b = (int)(grow >> 10); n = (int)(grow & 1023) + 1; }
        else           { b = (int)(grow / NSEQ); n = (int)(grow % NSEQ); }
        int col = c0 + c8;
        u16* dst; int c2;
        bool isV = (MODE == 0 && col >= 768);
        if (isV) { dst = Ob1; c2 = col - 768; }   // 768 not pow2: subtract
        else     { dst = Ob0; c2 = col; }
        int d0 = c2 & 63;
        if (!isV) {
            u16 e[8];
            unsigned wv[4] = {val.x, val.y, val.z, val.w};
            #pragma unroll
            for (int j = 0; j < 4; j++) { e[2*j] = (u16)(wv[j] & 0xFFFFu); e[2*j+1] = (u16)(wv[j] >> 16); }
            bool doro = (d0 < 32) && (n >= 1);
            if (MODE == 1 || doro) {
                float f[8];
                #pragma unroll
                for (int j = 0; j < 8; j++) f[j] = bf2f(e[j]);
                if (MODE == 1) {
                    #pragma unroll
                    for (int j = 0; j < 8; j++) f[j] *= 0.125f;   // fold softmax scale into q (exact)
                }
                if (doro) {
                    int pos = n - 1;
                    const float* cp = cosb + pos * 32 + d0;
                    const float* sp = sinb + pos * 32 + d0;
                    float4 cv0 = *(const float4*)cp, cv1 = *(const float4*)(cp + 4);
                    float4 sv0 = *(const float4*)sp, sv1 = *(const float4*)(sp + 4);
                    float ca[8] = {cv0.x, cv0.y, cv0.z, cv0.w, cv1.x, cv1.y, cv1.z, cv1.w};
                    float sa[8] = {sv0.x, sv0.y, sv0.z, sv0.w, sv1.x, sv1.y, sv1.z, sv1.w};
                    #pragma unroll
                    for (int pr = 0; pr < 4; pr++) {
                        float a = f[2*pr], bb2 = f[2*pr+1];
                        f[2*pr]   = a   * ca[2*pr]   - bb2 * sa[2*pr];
                        f[2*pr+1] = bb2 * ca[2*pr+1] + a   * sa[2*pr+1];
                    }
                }
                #pragma unroll
                for (int j = 0; j < 8; j++) e[j] = f2bf(f[j]);
            }
            #pragma unroll
            for (int j = 0; j < 4; j++) wv[j] = (unsigned)e[2*j] | ((unsigned)e[2*j+1] << 16);
            val = make_uint4(wv[0], wv[1], wv[2], wv[3]);
        }
        *(uint4*)(dst + ((size_t)(b * NHEADS + (c2 >> 6)) * NSEQ + n) * DHEAD + (c2 & 63)) = val;
    }
}

// ---------------- V [bh][1025][64] -> Vt [bh][64][VTP] ----------------
__global__ void vt_kernel(const u16* __restrict__ v, u16* __restrict__ Vt)
{
    __shared__ u16 tile[32][33];
    int bh = blockIdx.z;
    int n0 = blockIdx.x * 32, d0 = blockIdx.y * 32;
    for (int i = threadIdx.y; i < 32; i += 8) {
        int n = n0 + i;
        tile[i][threadIdx.x] = (n < NSEQ) ? v[((size_t)bh * NSEQ + n) * 64 + d0 + threadIdx.x] : (u16)0;
    }
    __syncthreads();
    for (int i = threadIdx.y; i < 32; i += 8) {
        int n = n0 + threadIdx.x;
        if (n < VTP) Vt[((size_t)bh * 64 + d0 + i) * VTP + n] = tile[threadIdx.x][i];
    }
}

// ---------------- flash attention: reg-Q, double-buffered async K/V, max-free softmax --
// q is pre-scaled by 1/8 upstream -> p = exp(sf) directly. Logits bounded; garbage in
// j>=NSEQ / i>=NSEQ lanes is nullified by the mask / unstored rows.
__launch_bounds__(256)
__global__ void attn_kernel(const u16* __restrict__ q, const u16* __restrict__ k,
                            const u16* __restrict__ Vt, u16* __restrict__ o)
{
    __shared__ u16 Kb[2][64 * 64];
    __shared__ u16 Vb[2][64 * 64];
    __shared__ u16 Ps[4 * 16 * LDP];  // per-wave P tile
    const int tid  = threadIdx.x;
    const int wave = tid >> 6, lane = tid & 63;
    const int q8 = lane >> 4, cc = lane & 15;
    const int bh = blockIdx.x;        // 96%8==0 -> all q-tiles of a head share an XCD
    const int i0 = blockIdx.y * 64;
    const int b = bh / NHEADS, h = bh % NHEADS;
    const size_t kbase  = (size_t)bh * NSEQ * 64;
    const size_t vtbase = (size_t)bh * 64 * VTP;

    // Q fragments: invariant across j-tiles -> registers, straight from global
    bf16x8 aq[2];
    {
        const u16* qp = q + kbase + (size_t)(i0 + wave * 16 + cc) * 64;
        aq[0] = *(const bf16x8*)(qp + q8 * 8);
        aq[1] = *(const bf16x8*)(qp + 32 + q8 * 8);
    }

    auto stage = [&](int jt, int buf) {
        int j0 = jt * 64;
        #pragma unroll
        for (int p = 0; p < 2; p++) {
            int chunk = wave * 128 + p * 64 + lane;       // 512 chunks per 64x64 tile
            int row = chunk >> 3, cs = chunk & 7;
            int src = cs ^ (row & 7);
            u16* kd = Kb[buf] + (size_t)(wave * 128 + p * 64) * 8;  // wave-uniform base
            u16* vd = Vb[buf] + (size_t)(wave * 128 + p * 64) * 8;
            gl2lds16(k  + kbase  + (size_t)(j0 + row) * 64 + src * 8, kd);
            gl2lds16(Vt + vtbase + (size_t)row * VTP + j0 + src * 8, vd);
        }
    };

    stage(0, 0);
    f32x4 O[4] = {};
    float lsum[4] = {0.f, 0.f, 0.f, 0.f};
    u16* Psw = Ps + wave * 16 * LDP;

    for (int jt = 0; jt < 17; jt++) {
        __syncthreads();                   // drains this wave's async loads; all waves synced
        const u16* Kc = Kb[jt & 1];
        const u16* Vc = Vb[jt & 1];
        if (jt < 16) stage(jt + 1, (jt + 1) & 1);   // prefetch overlaps compute below

        // S = Q K^T
        f32x4 sf[4] = {};
        #pragma unroll
        for (int ks = 0; ks < 2; ks++) {
            #pragma unroll
            for (int ni = 0; ni < 4; ni++) {
                bf16x8 bk = *(const bf16x8*)(Kc + (ni * 16 + cc) * 64 + (((ks * 4 + q8) ^ (cc & 7)) * 8));
                sf[ni] = __builtin_amdgcn_mfma_f32_16x16x32_bf16(aq[ks], bk, sf[ni], 0, 0, 0);
            }
        }

        // max-free softmax (q pre-scaled): p = exp(s)
        bool mask = (jt == 16);
        #pragma unroll
        for (int ni = 0; ni < 4; ni++) {
            #pragma unroll
            for (int r = 0; r < 4; r++) {
                float p = __expf(sf[ni][r]);
                if (mask && (1024 + ni * 16 + cc >= NSEQ)) p = 0.f;
                lsum[r] += p;
                unsigned u; __builtin_memcpy(&u, &p, 4);
                Psw[(q8 * 4 + r) * LDP + ni * 16 + cc] = (u16)((u + 0x8000u) >> 16);  // fast round
            }
        }

        // O += P V
        #pragma unroll
        for (int ks = 0; ks < 2; ks++) {
            bf16x8 pa = *(const bf16x8*)(Psw + cc * LDP + ks * 32 + q8 * 8);
            #pragma unroll
            for (int ni = 0; ni < 4; ni++) {
                bf16x8 vb = *(const bf16x8*)(Vc + (ni * 16 + cc) * 64 + (((ks * 4 + q8) ^ (cc & 7)) * 8));
                O[ni] = __builtin_amdgcn_mfma_f32_16x16x32_bf16(pa, vb, O[ni], 0, 0, 0);
            }
        }
    }

    #pragma unroll
    for (int r = 0; r < 4; r++) {
        lsum[r] += __shfl_xor(lsum[r], 1, 64);
        lsum[r] += __shfl_xor(lsum[r], 2, 64);
        lsum[r] += __shfl_xor(lsum[r], 4, 64);
        lsum[r] += __shfl_xor(lsum[r], 8, 64);
    }
    #pragma unroll
    for (int r = 0; r < 4; r++) {
        int i = i0 + wave * 16 + q8 * 4 + r;
        if (i >= NSEQ) continue;
        float inv = 1.0f / lsum[r];
        #pragma unroll
        for (int ni = 0; ni < 4; ni++)
            o[((size_t)(b * NSEQ + i)) * 768 + h * 64 + ni * 16 + cc] = f2bf(O[ni][r] * inv);
    }
}

extern "C" void kernel_launch(void* const* d_in, const int* in_sizes, int n_in,
                              void* d_out, int out_size, void* d_ws, size_t ws_size,
                              hipStream_t stream)
{
    const float* x     = (const float*)d_in[0];
    const float* sinb  = (const float*)d_in[1];
    const float* cosb  = (const float*)d_in[2];
    const float* ln_g  = (const float*)d_in[3];
    const float* ln_b  = (const float*)d_in[4];
    const float* dw_w  = (const float*)d_in[5];
    const float* pw_w  = (const float*)d_in[6];
    const float* kv_w  = (const float*)d_in[7];
    const float* out_w = (const float*)d_in[8];
    const float* out_b = (const float*)d_in[9];
    (void)in_sizes; (void)n_in; (void)out_size; (void)ws_size;

    u16* ws = (u16*)d_ws;                      // offsets in ushort units
    u16* xn_bf    = ws;                        // 6,297,600 (reused as attn output)
    u16* dwout_bf = ws + 6297600;              // 6,291,456
    u16* q_bf     = ws + 12589056;             // 6,297,600
    u16* k_bf     = ws + 18886656;             // 6,297,600
    u16* v_bf     = ws + 25184256;             // 6,297,600
    u16* Vt       = ws + 31481856;             // 6,389,760 (96*64*1040)
    u16* pw_bf    = ws + 37871616;             // 589,824
    u16* kv_wT    = ws + 38461440;             // 1,179,648
    u16* out_wT   = ws + 39641088;             // 589,824  -> 40,230,912 u16 = 80.5 MB
    float* dwT    = (float*)(ws + 40230912);   // 19,200 fp32
    u16* attn_bf  = xn_bf;                     // xn dead after kv GEMM

    ln_kernel      <<<NTOK, 256, 0, stream>>>(x, ln_g, ln_b, xn_bf, q_bf);
    preproc_kernel <<<4107, 256, 0, stream>>>(dw_w, pw_w, kv_w, out_w, dwT, pw_bf, kv_wT, out_wT);
    dw_kernel      <<<3072, 256, 0, stream>>>(xn_bf, dwT, dwout_bf);
    gemm_bf16<1>   <<<dim3(6, 64), 256, 0, stream>>>(dwout_bf, pw_bf, nullptr, q_bf, nullptr, nullptr, sinb, cosb, 8192);
    gemm_bf16<0>   <<<dim3(12, 65), 256, 0, stream>>>(xn_bf, kv_wT, nullptr, k_bf, v_bf, nullptr, sinb, cosb, NTOK);
    vt_kernel      <<<dim3(33, 2, 96), dim3(32, 8), 0, stream>>>(v_bf, Vt);
    attn_kernel    <<<dim3(96, 17), 256, 0, stream>>>(q_bf, k_bf, Vt, attn_bf);
    gemm_bf16<2>   <<<dim3(6, 65), 256, 0, stream>>>(attn_bf, out_wT, out_b, nullptr, nullptr, (float*)d_out, nullptr, nullptr, NTOK);
}

// Round 8
// 296.663 us; speedup vs baseline: 1.0338x; 1.0338x over previous
//
#include <hip/hip_runtime.h>
#include <cstddef>

#define NSEQ   1025
#define NBATCH 8
#define NTOK   8200      // 8*1025
#define DIMX   768
#define NHEADS 12
#define DHEAD  64
#define VTP    1040      // Vt row pitch (bf16), 16B-aligned
#define LDP    72        // Ps row pitch (bf16)
#define CP     136       // epilogue repack pitch (bf16)

typedef short bf16x8 __attribute__((ext_vector_type(8)));
typedef float f32x4  __attribute__((ext_vector_type(4)));
typedef unsigned short u16;

__device__ __forceinline__ float bf2f(u16 u) {
    unsigned v = (unsigned)u << 16; float f; __builtin_memcpy(&f, &v, 4); return f;
}
__device__ __forceinline__ u16 f2bf(float f) {
    unsigned u; __builtin_memcpy(&u, &f, 4);
    return (u16)((u + 0x7FFFu + ((u >> 16) & 1u)) >> 16);   // RNE
}

// async 16B global->LDS (dest = wave-uniform base + lane*16)
__device__ __forceinline__ void gl2lds16(const u16* g, u16* l) {
    __builtin_amdgcn_global_load_lds((__attribute__((address_space(1))) void*)g,
                                     (__attribute__((address_space(3))) void*)l, 16, 0, 0);
}

// ---------------- LayerNorm (+ fused cls->q scatter, q pre-scaled 1/8) ----------------
__launch_bounds__(256)
__global__ void ln_kernel(const float* __restrict__ x, const float* __restrict__ g,
                          const float* __restrict__ bb, u16* __restrict__ xn,
                          u16* __restrict__ qout)
{
    int t = blockIdx.x, tid = threadIdx.x;
    const float* xp = x + (size_t)t * DIMX;
    float v0 = xp[tid], v1 = xp[tid + 256], v2 = xp[tid + 512];
    float s  = v0 + v1 + v2;
    float ss = v0*v0 + v1*v1 + v2*v2;
    for (int off = 32; off > 0; off >>= 1) {
        s  += __shfl_down(s,  off, 64);
        ss += __shfl_down(ss, off, 64);
    }
    __shared__ float red[8];
    __shared__ float stats[2];
    int w = tid >> 6, lane = tid & 63;
    if (lane == 0) { red[w] = s; red[4 + w] = ss; }
    __syncthreads();
    if (tid == 0) {
        float S  = red[0] + red[1] + red[2] + red[3];
        float SS = red[4] + red[5] + red[6] + red[7];
        float mu  = S * (1.0f / DIMX);
        float var = SS * (1.0f / DIMX) - mu * mu;
        stats[0] = mu; stats[1] = rsqrtf(var + 1e-5f);
    }
    __syncthreads();
    float mu = stats[0], rs = stats[1];
    float y0 = (v0 - mu) * rs * g[tid]       + bb[tid];
    float y1 = (v1 - mu) * rs * g[tid + 256] + bb[tid + 256];
    float y2 = (v2 - mu) * rs * g[tid + 512] + bb[tid + 512];
    u16* op = xn + (size_t)t * DIMX;
    op[tid] = f2bf(y0); op[tid + 256] = f2bf(y1); op[tid + 512] = f2bf(y2);
    int bq = t / NSEQ;
    if (t == bq * NSEQ) {   // cls token -> q row 0, head layout, pre-scaled by 1/8
        int c0 = tid, c1 = tid + 256, c2 = tid + 512;
        qout[((size_t)(bq * NHEADS + (c0 >> 6)) * NSEQ) * DHEAD + (c0 & 63)] = f2bf(y0 * 0.125f);
        qout[((size_t)(bq * NHEADS + (c1 >> 6)) * NSEQ) * DHEAD + (c1 & 63)] = f2bf(y1 * 0.125f);
        qout[((size_t)(bq * NHEADS + (c2 >> 6)) * NSEQ) * DHEAD + (c2 & 63)] = f2bf(y2 * 0.125f);
    }
}

// ---------------- fused weight preprocessing ----------------
__launch_bounds__(256)
__global__ void preproc_kernel(const float* __restrict__ dw_w, const float* __restrict__ pw_w,
                               const float* __restrict__ kv_w, const float* __restrict__ out_w,
                               float* __restrict__ dwT, u16* __restrict__ pw_bf,
                               u16* __restrict__ kv_wT, u16* __restrict__ out_wT)
{
    __shared__ float tile[32][33];
    int blk = blockIdx.x, tid = threadIdx.x;
    if (blk < 75) {
        int idx = blk * 256 + tid;
        if (idx < 768 * 25) {
            int c = idx / 25, wi = idx % 25;
            dwT[wi * 768 + c] = dw_w[idx];
        }
        return;
    }
    if (blk < 2379) {
        int i = (blk - 75) * 256 + tid;
        pw_bf[i] = f2bf(pw_w[i]);
        return;
    }
    const float* in; u16* out; int R, C, bx, by;
    if (blk < 3531) {
        int t2 = blk - 2379; bx = t2 % 48; by = t2 / 48;
        in = kv_w; out = kv_wT; R = 768; C = 1536;
    } else {
        int t2 = blk - 3531; bx = t2 % 24; by = t2 / 24;
        in = out_w; out = out_wT; R = 768; C = 768;
    }
    int tx = tid & 31, ty = tid >> 5;
    int xg = bx * 32 + tx, y0 = by * 32;
    for (int i = ty; i < 32; i += 8)
        tile[i][tx] = in[(size_t)(y0 + i) * C + xg];
    __syncthreads();
    int xo = by * 32 + tx, yo0 = bx * 32;
    for (int i = ty; i < 32; i += 8)
        out[(size_t)(yo0 + i) * R + xo] = f2bf(tile[tx][i]);
}

// ---------------- depthwise 5x5 conv, vectorized: 8 channels/thread ----------------
__launch_bounds__(256)
__global__ void dw_kernel(const u16* __restrict__ xn, const float* __restrict__ wt,
                          u16* __restrict__ out)
{
    int gid = blockIdx.x * 256 + threadIdx.x;      // 786432 = 8192 px * 96 groups
    int pix = gid / 96, cg = gid - pix * 96;
    int c = cg * 8;
    int b = pix >> 10, p = pix & 1023, y = p >> 5, x0 = p & 31;
    float acc[8] = {};
    for (int dy = 0; dy < 5; dy++) {
        int yy = y + dy - 2;
        if ((unsigned)yy >= 32u) continue;
        for (int dx = 0; dx < 5; dx++) {
            int xx = x0 + dx - 2;
            if ((unsigned)xx >= 32u) continue;
            const u16* ip = xn + ((size_t)(b * NSEQ) + 1 + yy * 32 + xx) * DIMX + c;
            uint4 iv = *(const uint4*)ip;
            const float* wp = wt + (dy * 5 + dx) * DIMX + c;
            float4 w0 = *(const float4*)wp;
            float4 w1 = *(const float4*)(wp + 4);
            acc[0] += bf2f((u16)(iv.x & 0xFFFFu)) * w0.x;
            acc[1] += bf2f((u16)(iv.x >> 16))     * w0.y;
            acc[2] += bf2f((u16)(iv.y & 0xFFFFu)) * w0.z;
            acc[3] += bf2f((u16)(iv.y >> 16))     * w0.w;
            acc[4] += bf2f((u16)(iv.z & 0xFFFFu)) * w1.x;
            acc[5] += bf2f((u16)(iv.z >> 16))     * w1.y;
            acc[6] += bf2f((u16)(iv.w & 0xFFFFu)) * w1.z;
            acc[7] += bf2f((u16)(iv.w >> 16))     * w1.w;
        }
    }
    uint4 ov;
    ov.x = (unsigned)f2bf(acc[0]) | ((unsigned)f2bf(acc[1]) << 16);
    ov.y = (unsigned)f2bf(acc[2]) | ((unsigned)f2bf(acc[3]) << 16);
    ov.z = (unsigned)f2bf(acc[4]) | ((unsigned)f2bf(acc[5]) << 16);
    ov.w = (unsigned)f2bf(acc[6]) | ((unsigned)f2bf(acc[7]) << 16);
    *(uint4*)(out + (size_t)pix * DIMX + c) = ov;
}

// ---------------- merged projection GEMM (kv + pw in one grid) ----------------
// blocks [0,780): kv  — A=xn [8200x768], B=kv_wT -> K (rope) / V head-scatter
// blocks [780,1164): pw — A=dwout [8192x768], B=pw_bf -> q (scale+rope, n=pix+1)
__launch_bounds__(256)
__global__ void gemm_proj(const u16* __restrict__ xn, const u16* __restrict__ dwout,
                          const u16* __restrict__ kvB, const u16* __restrict__ pwB,
                          u16* __restrict__ kOut, u16* __restrict__ vOut,
                          u16* __restrict__ qOut,
                          const float* __restrict__ sinb, const float* __restrict__ cosb)
{
    __shared__ u16 smem[128 * CP];          // As(16KB)+Bs(16KB) then Ct repack
    u16* As = smem;
    u16* Bs = smem + 8192;
    const int tid  = threadIdx.x;
    const int wave = tid >> 6, lane = tid & 63;
    const int q8 = lane >> 4, cc = lane & 15;
    const int wr = wave >> 1, wc = wave & 1;

    int bid = blockIdx.x;
    int mode, bx, M;
    long r0;
    const u16 *A, *Bn;
    if (bid < 780) { mode = 0; bx = bid % 12; r0 = (long)(bid / 12) * 128; A = xn;    Bn = kvB; M = NTOK; }
    else { int t2 = bid - 780; mode = 1; bx = t2 % 6; r0 = (long)(t2 / 6) * 128; A = dwout; Bn = pwB; M = 8192; }
    const int c0 = bx * 128;
    u16* Ob0 = (mode == 0) ? kOut : qOut;

    f32x4 acc[4][4] = {};

    for (int k0 = 0; k0 < 768; k0 += 64) {
        __syncthreads();                    // prior iter's fragment reads done
        #pragma unroll
        for (int p = 0; p < 4; p++) {
            int chunk = wave * 256 + p * 64 + lane;      // 1024 chunks per 128x64 tile
            int row = chunk >> 3, cs = chunk & 7;
            int src = cs ^ (row & 7);                     // swizzled source chunk
            const u16* ga = A  + (size_t)(r0 + row) * 768 + k0 + src * 8;
            const u16* gb = Bn + (size_t)(c0 + row) * 768 + k0 + src * 8;
            u16* la = As + (size_t)(wave * 256 + p * 64) * 8;   // wave-uniform base
            u16* lb = Bs + (size_t)(wave * 256 + p * 64) * 8;
            gl2lds16(ga, la);
            gl2lds16(gb, lb);
        }
        __syncthreads();                    // drains vmcnt -> LDS valid
        #pragma unroll
        for (int ks = 0; ks < 2; ks++) {
            const int chsw = (((ks * 4 + q8) ^ (cc & 7)) * 8);
            bf16x8 af[4], bfr[4];
            #pragma unroll
            for (int mi = 0; mi < 4; mi++)
                af[mi] = *(const bf16x8*)(As + (wr * 64 + mi * 16 + cc) * 64 + chsw);
            #pragma unroll
            for (int ni = 0; ni < 4; ni++)
                bfr[ni] = *(const bf16x8*)(Bs + (wc * 64 + ni * 16 + cc) * 64 + chsw);
            #pragma unroll
            for (int mi = 0; mi < 4; mi++)
                #pragma unroll
                for (int ni = 0; ni < 4; ni++)
                    acc[mi][ni] = __builtin_amdgcn_mfma_f32_16x16x32_bf16(af[mi], bfr[ni], acc[mi][ni], 0, 0, 0);
        }
    }

    // repack through LDS, then coalesced 16B stores in head layout (+rope/scale)
    __syncthreads();                        // all fragment reads done; reuse smem as Ct
    #pragma unroll
    for (int mi = 0; mi < 4; mi++)
        #pragma unroll
        for (int r = 0; r < 4; r++) {
            int lr = wr * 64 + mi * 16 + q8 * 4 + r;
            #pragma unroll
            for (int ni = 0; ni < 4; ni++)
                smem[lr * CP + wc * 64 + ni * 16 + cc] = f2bf(acc[mi][ni][r]);
        }
    __syncthreads();
    #pragma unroll
    for (int p = 0; p < 8; p++) {
        int id = p * 256 + tid;             // 2048 uint4 chunks (128 rows x 16)
        int row = id >> 4, c8 = (id & 15) * 8;
        long grow = r0 + row;
        if (grow >= M) continue;
        uint4 val = *(const uint4*)(smem + row * CP + c8);
        int b, n;
        if (mode == 1) { b = (int)(grow >> 10); n = (int)(grow & 1023) + 1; }
        else           { b = (int)(grow / NSEQ); n = (int)(grow % NSEQ); }
        int col = c0 + c8;
        u16* dst; int c2;
        bool isV = (mode == 0 && col >= 768);
        if (isV) { dst = vOut; c2 = col - 768; }   // 768 not pow2: subtract
        else     { dst = Ob0;  c2 = col; }
        int d0 = c2 & 63;
        if (!isV) {
            u16 e[8];
            unsigned wv[4] = {val.x, val.y, val.z, val.w};
            #pragma unroll
            for (int j = 0; j < 4; j++) { e[2*j] = (u16)(wv[j] & 0xFFFFu); e[2*j+1] = (u16)(wv[j] >> 16); }
            bool doro = (d0 < 32) && (n >= 1);
            if (mode == 1 || doro) {
                float f[8];
                #pragma unroll
                for (int j = 0; j < 8; j++) f[j] = bf2f(e[j]);
                if (mode == 1) {
                    #pragma unroll
                    for (int j = 0; j < 8; j++) f[j] *= 0.125f;   // fold softmax scale into q (exact)
                }
                if (doro) {
                    int pos = n - 1;
                    const float* cp = cosb + pos * 32 + d0;
                    const float* sp = sinb + pos * 32 + d0;
                    float4 cv0 = *(const float4*)cp, cv1 = *(const float4*)(cp + 4);
                    float4 sv0 = *(const float4*)sp, sv1 = *(const float4*)(sp + 4);
                    float ca[8] = {cv0.x, cv0.y, cv0.z, cv0.w, cv1.x, cv1.y, cv1.z, cv1.w};
                    float sa[8] = {sv0.x, sv0.y, sv0.z, sv0.w, sv1.x, sv1.y, sv1.z, sv1.w};
                    #pragma unroll
                    for (int pr = 0; pr < 4; pr++) {
                        float a = f[2*pr], bb2 = f[2*pr+1];
                        f[2*pr]   = a   * ca[2*pr]   - bb2 * sa[2*pr];
                        f[2*pr+1] = bb2 * ca[2*pr+1] + a   * sa[2*pr+1];
                    }
                }
                #pragma unroll
                for (int j = 0; j < 8; j++) e[j] = f2bf(f[j]);
            }
            #pragma unroll
            for (int j = 0; j < 4; j++) wv[j] = (unsigned)e[2*j] | ((unsigned)e[2*j+1] << 16);
            val = make_uint4(wv[0], wv[1], wv[2], wv[3]);
        }
        *(uint4*)(dst + ((size_t)(b * NHEADS + (c2 >> 6)) * NSEQ + n) * DHEAD + (c2 & 63)) = val;
    }
}

// ---------------- output GEMM: fp32 d_out + bias ----------------
__launch_bounds__(256)
__global__ void gemm_out(const u16* __restrict__ A, const u16* __restrict__ Bn,
                         const float* __restrict__ bias, float* __restrict__ Of, int M)
{
    __shared__ u16 smem[32768 / 2 * 2];     // As+Bs 32KB
    u16* As = smem;
    u16* Bs = smem + 8192;
    const int tid  = threadIdx.x;
    const int wave = tid >> 6, lane = tid & 63;
    const int q8 = lane >> 4, cc = lane & 15;
    const int wr = wave >> 1, wc = wave & 1;
    const long r0 = (long)blockIdx.y * 128;
    const int  c0 = blockIdx.x * 128;

    f32x4 acc[4][4] = {};

    for (int k0 = 0; k0 < 768; k0 += 64) {
        __syncthreads();
        #pragma unroll
        for (int p = 0; p < 4; p++) {
            int chunk = wave * 256 + p * 64 + lane;
            int row = chunk >> 3, cs = chunk & 7;
            int src = cs ^ (row & 7);
            const u16* ga = A  + (size_t)(r0 + row) * 768 + k0 + src * 8;
            const u16* gb = Bn + (size_t)(c0 + row) * 768 + k0 + src * 8;
            u16* la = As + (size_t)(wave * 256 + p * 64) * 8;
            u16* lb = Bs + (size_t)(wave * 256 + p * 64) * 8;
            gl2lds16(ga, la);
            gl2lds16(gb, lb);
        }
        __syncthreads();
        #pragma unroll
        for (int ks = 0; ks < 2; ks++) {
            const int chsw = (((ks * 4 + q8) ^ (cc & 7)) * 8);
            bf16x8 af[4], bfr[4];
            #pragma unroll
            for (int mi = 0; mi < 4; mi++)
                af[mi] = *(const bf16x8*)(As + (wr * 64 + mi * 16 + cc) * 64 + chsw);
            #pragma unroll
            for (int ni = 0; ni < 4; ni++)
                bfr[ni] = *(const bf16x8*)(Bs + (wc * 64 + ni * 16 + cc) * 64 + chsw);
            #pragma unroll
            for (int mi = 0; mi < 4; mi++)
                #pragma unroll
                for (int ni = 0; ni < 4; ni++)
                    acc[mi][ni] = __builtin_amdgcn_mfma_f32_16x16x32_bf16(af[mi], bfr[ni], acc[mi][ni], 0, 0, 0);
        }
    }
    #pragma unroll
    for (int mi = 0; mi < 4; mi++) {
        #pragma unroll
        for (int r = 0; r < 4; r++) {
            long row = r0 + wr * 64 + mi * 16 + q8 * 4 + r;
            if (row >= M) continue;
            #pragma unroll
            for (int ni = 0; ni < 4; ni++) {
                int col = c0 + wc * 64 + ni * 16 + cc;
                Of[(size_t)row * 768 + col] = acc[mi][ni][r] + bias[col];
            }
        }
    }
}

// ---------------- V [bh][1025][64] -> Vt [bh][64][VTP] ----------------
__global__ void vt_kernel(const u16* __restrict__ v, u16* __restrict__ Vt)
{
    __shared__ u16 tile[32][33];
    int bh = blockIdx.z;
    int n0 = blockIdx.x * 32, d0 = blockIdx.y * 32;
    for (int i = threadIdx.y; i < 32; i += 8) {
        int n = n0 + i;
        tile[i][threadIdx.x] = (n < NSEQ) ? v[((size_t)bh * NSEQ + n) * 64 + d0 + threadIdx.x] : (u16)0;
    }
    __syncthreads();
    for (int i = threadIdx.y; i < 32; i += 8) {
        int n = n0 + threadIdx.x;
        if (n < VTP) Vt[((size_t)bh * 64 + d0 + i) * VTP + n] = tile[threadIdx.x][i];
    }
}

// ---------------- flash attention: 128-row Q tile, reg-Q, dbuf async K/V ----------
// 4 waves x 32 rows (two 16-row A-frag groups). K/V staging, barriers, and bk/vb
// fragment loads shared across both groups -> 32 MFMA per tile per wave.
__launch_bounds__(256)
__global__ void attn_kernel(const u16* __restrict__ q, const u16* __restrict__ k,
                            const u16* __restrict__ Vt, u16* __restrict__ o)
{
    __shared__ u16 Kb[2][64 * 64];
    __shared__ u16 Vb[2][64 * 64];
    __shared__ u16 Ps[4 * 32 * LDP];  // per-wave 32-row P tile
    const int tid  = threadIdx.x;
    const int wave = tid >> 6, lane = tid & 63;
    const int q8 = lane >> 4, cc = lane & 15;
    const int bh = blockIdx.x;        // 96%8==0 -> all q-tiles of a head share an XCD
    const int i0 = blockIdx.y * 128;
    const int b = bh / NHEADS, h = bh % NHEADS;
    const size_t kbase  = (size_t)bh * NSEQ * 64;
    const size_t vtbase = (size_t)bh * 64 * VTP;

    // Q fragments (2 row-groups x 2 ks): invariant across j-tiles -> registers
    bf16x8 aq[2][2];
    #pragma unroll
    for (int mi = 0; mi < 2; mi++) {
        const u16* qp = q + kbase + (size_t)(i0 + wave * 32 + mi * 16 + cc) * 64;
        aq[mi][0] = *(const bf16x8*)(qp + q8 * 8);
        aq[mi][1] = *(const bf16x8*)(qp + 32 + q8 * 8);
    }

    auto stage = [&](int jt, int buf) {
        int j0 = jt * 64;
        #pragma unroll
        for (int p = 0; p < 2; p++) {
            int chunk = wave * 128 + p * 64 + lane;       // 512 chunks per 64x64 tile
            int row = chunk >> 3, cs = chunk & 7;
            int src = cs ^ (row & 7);
            u16* kd = Kb[buf] + (size_t)(wave * 128 + p * 64) * 8;  // wave-uniform base
            u16* vd = Vb[buf] + (size_t)(wave * 128 + p * 64) * 8;
            gl2lds16(k  + kbase  + (size_t)(j0 + row) * 64 + src * 8, kd);
            gl2lds16(Vt + vtbase + (size_t)row * VTP + j0 + src * 8, vd);
        }
    };

    stage(0, 0);
    f32x4 O[2][4] = {};
    float lsum[2][4] = {};
    u16* Psw = Ps + wave * 32 * LDP;

    for (int jt = 0; jt < 17; jt++) {
        __syncthreads();                   // drains async loads; all waves synced
        const u16* Kc = Kb[jt & 1];
        const u16* Vc = Vb[jt & 1];
        if (jt < 16) stage(jt + 1, (jt + 1) & 1);   // prefetch overlaps compute below

        // S = Q K^T
        f32x4 sf[2][4] = {};
        #pragma unroll
        for (int ks = 0; ks < 2; ks++) {
            #pragma unroll
            for (int ni = 0; ni < 4; ni++) {
                bf16x8 bk = *(const bf16x8*)(Kc + (ni * 16 + cc) * 64 + (((ks * 4 + q8) ^ (cc & 7)) * 8));
                #pragma unroll
                for (int mi = 0; mi < 2; mi++)
                    sf[mi][ni] = __builtin_amdgcn_mfma_f32_16x16x32_bf16(aq[mi][ks], bk, sf[mi][ni], 0, 0, 0);
            }
        }

        // max-free softmax (q pre-scaled): p = exp(s)
        bool mask = (jt == 16);
        #pragma unroll
        for (int mi = 0; mi < 2; mi++)
            #pragma unroll
            for (int ni = 0; ni < 4; ni++)
                #pragma unroll
                for (int r = 0; r < 4; r++) {
                    float p = __expf(sf[mi][ni][r]);
                    if (mask && (1024 + ni * 16 + cc >= NSEQ)) p = 0.f;
                    lsum[mi][r] += p;
                    unsigned u; __builtin_memcpy(&u, &p, 4);
                    Psw[(mi * 16 + q8 * 4 + r) * LDP + ni * 16 + cc] = (u16)((u + 0x8000u) >> 16);
                }

        // O += P V  (wave-private Ps: compiler's lgkmcnt covers write->read)
        #pragma unroll
        for (int ks = 0; ks < 2; ks++) {
            bf16x8 pa[2];
            #pragma unroll
            for (int mi = 0; mi < 2; mi++)
                pa[mi] = *(const bf16x8*)(Psw + (mi * 16 + cc) * LDP + ks * 32 + q8 * 8);
            #pragma unroll
            for (int ni = 0; ni < 4; ni++) {
                bf16x8 vb = *(const bf16x8*)(Vc + (ni * 16 + cc) * 64 + (((ks * 4 + q8) ^ (cc & 7)) * 8));
                #pragma unroll
                for (int mi = 0; mi < 2; mi++)
                    O[mi][ni] = __builtin_amdgcn_mfma_f32_16x16x32_bf16(pa[mi], vb, O[mi][ni], 0, 0, 0);
            }
        }
    }

    #pragma unroll
    for (int mi = 0; mi < 2; mi++)
        #pragma unroll
        for (int r = 0; r < 4; r++) {
            lsum[mi][r] += __shfl_xor(lsum[mi][r], 1, 64);
            lsum[mi][r] += __shfl_xor(lsum[mi][r], 2, 64);
            lsum[mi][r] += __shfl_xor(lsum[mi][r], 4, 64);
            lsum[mi][r] += __shfl_xor(lsum[mi][r], 8, 64);
        }
    #pragma unroll
    for (int mi = 0; mi < 2; mi++)
        #pragma unroll
        for (int r = 0; r < 4; r++) {
            int i = i0 + wave * 32 + mi * 16 + q8 * 4 + r;
            if (i >= NSEQ) continue;
            float inv = 1.0f / lsum[mi][r];
            #pragma unroll
            for (int ni = 0; ni < 4; ni++)
                o[((size_t)(b * NSEQ + i)) * 768 + h * 64 + ni * 16 + cc] = f2bf(O[mi][ni][r] * inv);
        }
}

extern "C" void kernel_launch(void* const* d_in, const int* in_sizes, int n_in,
                              void* d_out, int out_size, void* d_ws, size_t ws_size,
                              hipStream_t stream)
{
    const float* x     = (const float*)d_in[0];
    const float* sinb  = (const float*)d_in[1];
    const float* cosb  = (const float*)d_in[2];
    const float* ln_g  = (const float*)d_in[3];
    const float* ln_b  = (const float*)d_in[4];
    const float* dw_w  = (const float*)d_in[5];
    const float* pw_w  = (const float*)d_in[6];
    const float* kv_w  = (const float*)d_in[7];
    const float* out_w = (const float*)d_in[8];
    const float* out_b = (const float*)d_in[9];
    (void)in_sizes; (void)n_in; (void)out_size; (void)ws_size;

    u16* ws = (u16*)d_ws;                      // offsets in ushort units
    u16* xn_bf    = ws;                        // 6,297,600 (reused as attn output)
    u16* dwout_bf = ws + 6297600;              // 6,291,456
    u16* q_bf     = ws + 12589056;             // 6,297,600
    u16* k_bf     = ws + 18886656;             // 6,297,600
    u16* v_bf     = ws + 25184256;             // 6,297,600
    u16* Vt       = ws + 31481856;             // 6,389,760 (96*64*1040)
    u16* pw_bf    = ws + 37871616;             // 589,824
    u16* kv_wT    = ws + 38461440;             // 1,179,648
    u16* out_wT   = ws + 39641088;             // 589,824  -> 40,230,912 u16 = 80.5 MB
    float* dwT    = (float*)(ws + 40230912);   // 19,200 fp32
    u16* attn_bf  = xn_bf;                     // xn dead after kv GEMM

    ln_kernel      <<<NTOK, 256, 0, stream>>>(x, ln_g, ln_b, xn_bf, q_bf);
    preproc_kernel <<<4107, 256, 0, stream>>>(dw_w, pw_w, kv_w, out_w, dwT, pw_bf, kv_wT, out_wT);
    dw_kernel      <<<3072, 256, 0, stream>>>(xn_bf, dwT, dwout_bf);
    gemm_proj      <<<1164, 256, 0, stream>>>(xn_bf, dwout_bf, kv_wT, pw_bf, k_bf, v_bf, q_bf, sinb, cosb);
    vt_kernel      <<<dim3(33, 2, 96), dim3(32, 8), 0, stream>>>(v_bf, Vt);
    attn_kernel    <<<dim3(96, 9), 256, 0, stream>>>(q_bf, k_bf, Vt, attn_bf);
    gemm_out       <<<dim3(6, 65), 256, 0, stream>>>(attn_bf, out_wT, out_b, (float*)d_out, NTOK);
}

// Round 9
// 274.278 us; speedup vs baseline: 1.1182x; 1.0816x over previous
//
#include <hip/hip_runtime.h>
#include <cstddef>

#define NSEQ   1025
#define NBATCH 8
#define NTOK   8200      // 8*1025
#define DIMX   768
#define NHEADS 12
#define DHEAD  64
#define VTP3   8320      // Vt row pitch (bf16): 65 col-tiles * 128; col s = b*1032 + n
#define LDP    72        // Ps row pitch (bf16)
#define CP     136       // epilogue repack pitch (bf16)

typedef short bf16x8 __attribute__((ext_vector_type(8)));
typedef float f32x4  __attribute__((ext_vector_type(4)));
typedef unsigned short u16;

__device__ __forceinline__ float bf2f(u16 u) {
    unsigned v = (unsigned)u << 16; float f; __builtin_memcpy(&f, &v, 4); return f;
}
__device__ __forceinline__ u16 f2bf(float f) {
    unsigned u; __builtin_memcpy(&u, &f, 4);
    return (u16)((u + 0x7FFFu + ((u >> 16) & 1u)) >> 16);   // RNE
}

// async 16B global->LDS (dest = wave-uniform base + lane*16)
__device__ __forceinline__ void gl2lds16(const u16* g, u16* l) {
    __builtin_amdgcn_global_load_lds((__attribute__((address_space(1))) void*)g,
                                     (__attribute__((address_space(3))) void*)l, 16, 0, 0);
}

// ---------------- fused LayerNorm (+cls->q) and weight preprocessing ----------------
// blocks [0, NTOK): LN per token   blocks [NTOK, NTOK+4107): weight preproc
__launch_bounds__(256)
__global__ void ln_pre_kernel(const float* __restrict__ x, const float* __restrict__ g,
                              const float* __restrict__ bb, u16* __restrict__ xn,
                              u16* __restrict__ qout,
                              const float* __restrict__ dw_w, const float* __restrict__ pw_w,
                              const float* __restrict__ kv_w, const float* __restrict__ out_w,
                              float* __restrict__ dwT, u16* __restrict__ pw_bf,
                              u16* __restrict__ kv_wT, u16* __restrict__ out_wT)
{
    __shared__ float red[8];
    __shared__ float stats[2];
    __shared__ float tile[32][33];
    int tid = threadIdx.x;
    if (blockIdx.x < NTOK) {
        int t = blockIdx.x;
        const float* xp = x + (size_t)t * DIMX;
        float v0 = xp[tid], v1 = xp[tid + 256], v2 = xp[tid + 512];
        float s  = v0 + v1 + v2;
        float ss = v0*v0 + v1*v1 + v2*v2;
        for (int off = 32; off > 0; off >>= 1) {
            s  += __shfl_down(s,  off, 64);
            ss += __shfl_down(ss, off, 64);
        }
        int w = tid >> 6, lane = tid & 63;
        if (lane == 0) { red[w] = s; red[4 + w] = ss; }
        __syncthreads();
        if (tid == 0) {
            float S  = red[0] + red[1] + red[2] + red[3];
            float SS = red[4] + red[5] + red[6] + red[7];
            float mu  = S * (1.0f / DIMX);
            float var = SS * (1.0f / DIMX) - mu * mu;
            stats[0] = mu; stats[1] = rsqrtf(var + 1e-5f);
        }
        __syncthreads();
        float mu = stats[0], rs = stats[1];
        float y0 = (v0 - mu) * rs * g[tid]       + bb[tid];
        float y1 = (v1 - mu) * rs * g[tid + 256] + bb[tid + 256];
        float y2 = (v2 - mu) * rs * g[tid + 512] + bb[tid + 512];
        u16* op = xn + (size_t)t * DIMX;
        op[tid] = f2bf(y0); op[tid + 256] = f2bf(y1); op[tid + 512] = f2bf(y2);
        int bq = t / NSEQ;
        if (t == bq * NSEQ) {   // cls token -> q row 0, head layout, pre-scaled by 1/8
            int c0 = tid, c1 = tid + 256, c2 = tid + 512;
            qout[((size_t)(bq * NHEADS + (c0 >> 6)) * NSEQ) * DHEAD + (c0 & 63)] = f2bf(y0 * 0.125f);
            qout[((size_t)(bq * NHEADS + (c1 >> 6)) * NSEQ) * DHEAD + (c1 & 63)] = f2bf(y1 * 0.125f);
            qout[((size_t)(bq * NHEADS + (c2 >> 6)) * NSEQ) * DHEAD + (c2 & 63)] = f2bf(y2 * 0.125f);
        }
        return;
    }
    int blk = blockIdx.x - NTOK;
    if (blk < 75) {
        int idx = blk * 256 + tid;
        if (idx < 768 * 25) {
            int c = idx / 25, wi = idx % 25;
            dwT[wi * 768 + c] = dw_w[idx];
        }
        return;
    }
    if (blk < 2379) {
        int i = (blk - 75) * 256 + tid;
        pw_bf[i] = f2bf(pw_w[i]);
        return;
    }
    const float* in; u16* out; int R, C, bx, by;
    if (blk < 3531) {
        int t2 = blk - 2379; bx = t2 % 48; by = t2 / 48;
        in = kv_w; out = kv_wT; R = 768; C = 1536;
    } else {
        int t2 = blk - 3531; bx = t2 % 24; by = t2 / 24;
        in = out_w; out = out_wT; R = 768; C = 768;
    }
    int tx = tid & 31, ty = tid >> 5;
    int xg = bx * 32 + tx, y0 = by * 32;
    for (int i = ty; i < 32; i += 8)
        tile[i][tx] = in[(size_t)(y0 + i) * C + xg];
    __syncthreads();
    int xo = by * 32 + tx, yo0 = bx * 32;
    for (int i = ty; i < 32; i += 8)
        out[(size_t)(yo0 + i) * R + xo] = f2bf(tile[tx][i]);
}

// ---------------- depthwise 5x5 conv, vectorized: 8 channels/thread ----------------
__launch_bounds__(256)
__global__ void dw_kernel(const u16* __restrict__ xn, const float* __restrict__ wt,
                          u16* __restrict__ out)
{
    int gid = blockIdx.x * 256 + threadIdx.x;      // 786432 = 8192 px * 96 groups
    int pix = gid / 96, cg = gid - pix * 96;
    int c = cg * 8;
    int b = pix >> 10, p = pix & 1023, y = p >> 5, x0 = p & 31;
    float acc[8] = {};
    for (int dy = 0; dy < 5; dy++) {
        int yy = y + dy - 2;
        if ((unsigned)yy >= 32u) continue;
        for (int dx = 0; dx < 5; dx++) {
            int xx = x0 + dx - 2;
            if ((unsigned)xx >= 32u) continue;
            const u16* ip = xn + ((size_t)(b * NSEQ) + 1 + yy * 32 + xx) * DIMX + c;
            uint4 iv = *(const uint4*)ip;
            const float* wp = wt + (dy * 5 + dx) * DIMX + c;
            float4 w0 = *(const float4*)wp;
            float4 w1 = *(const float4*)(wp + 4);
            acc[0] += bf2f((u16)(iv.x & 0xFFFFu)) * w0.x;
            acc[1] += bf2f((u16)(iv.x >> 16))     * w0.y;
            acc[2] += bf2f((u16)(iv.y & 0xFFFFu)) * w0.z;
            acc[3] += bf2f((u16)(iv.y >> 16))     * w0.w;
            acc[4] += bf2f((u16)(iv.z & 0xFFFFu)) * w1.x;
            acc[5] += bf2f((u16)(iv.z >> 16))     * w1.y;
            acc[6] += bf2f((u16)(iv.w & 0xFFFFu)) * w1.z;
            acc[7] += bf2f((u16)(iv.w >> 16))     * w1.w;
        }
    }
    uint4 ov;
    ov.x = (unsigned)f2bf(acc[0]) | ((unsigned)f2bf(acc[1]) << 16);
    ov.y = (unsigned)f2bf(acc[2]) | ((unsigned)f2bf(acc[3]) << 16);
    ov.z = (unsigned)f2bf(acc[4]) | ((unsigned)f2bf(acc[5]) << 16);
    ov.w = (unsigned)f2bf(acc[6]) | ((unsigned)f2bf(acc[7]) << 16);
    *(uint4*)(out + (size_t)pix * DIMX + c) = ov;
}

// ---------------- merged projection GEMM: K, V^T, and q in one grid ----------------
// blocks [0,390):    K  — C[tok][768] = xn·kv_wT[0:768]^T  -> K head-scatter + rope
// blocks [390,780):  V^T — C[d=768][s=8320] = kv_wT[768:]·xn_pad^T -> Vt rows directly
//                    (s = b*1032 + n: per-batch n padded to 1032 so 8-aligned s-chunks
//                     give 16B-aligned Vt stores despite NSEQ=1025)
// blocks [780,1164): q  — C[8192][768] = dwout·pw_bf^T -> q head-scatter, 1/8 + rope
__launch_bounds__(256)
__global__ void gemm_proj(const u16* __restrict__ xn, const u16* __restrict__ dwout,
                          const u16* __restrict__ kvT, const u16* __restrict__ pwB,
                          u16* __restrict__ kOut, u16* __restrict__ VtOut,
                          u16* __restrict__ qOut,
                          const float* __restrict__ sinb, const float* __restrict__ cosb)
{
    __shared__ u16 smem[128 * CP];          // As(16KB)+Bs(16KB) then Ct repack
    u16* As = smem;
    u16* Bs = smem + 8192;
    const int tid  = threadIdx.x;
    const int wave = tid >> 6, lane = tid & 63;
    const int q8 = lane >> 4, cc = lane & 15;
    const int wr = wave >> 1, wc = wave & 1;

    int bid = blockIdx.x;
    int mode, c0;
    long r0;
    const u16 *A, *Bn;
    if (bid < 390)      { mode = 0; c0 = (bid % 6) * 128;  r0 = (long)(bid / 6) * 128;  A = xn;              Bn = kvT; }
    else if (bid < 780) { int t2 = bid - 390;
                          mode = 2; c0 = (t2 % 65) * 128;  r0 = (long)(t2 / 65) * 128; A = kvT + 768 * 768; Bn = xn; }
    else                { int t2 = bid - 780;
                          mode = 1; c0 = (t2 % 6) * 128;   r0 = (long)(t2 / 6) * 128;  A = dwout;           Bn = pwB; }

    f32x4 acc[4][4] = {};

    for (int k0 = 0; k0 < 768; k0 += 64) {
        __syncthreads();                    // prior iter's fragment reads done
        #pragma unroll
        for (int p = 0; p < 4; p++) {
            int chunk = wave * 256 + p * 64 + lane;      // 1024 chunks per 128x64 tile
            int row = chunk >> 3, cs = chunk & 7;
            int src = cs ^ (row & 7);                     // swizzled source chunk
            long brow;
            if (mode == 2) {                              // padded-token B row
                int s = c0 + row;
                int bb2 = s / 1032;
                brow = (long)bb2 * NSEQ + (s - bb2 * 1032);
            } else brow = c0 + row;
            const u16* ga = A  + (size_t)(r0 + row) * 768 + k0 + src * 8;
            const u16* gb = Bn + (size_t)brow * 768 + k0 + src * 8;
            u16* la = As + (size_t)(wave * 256 + p * 64) * 8;   // wave-uniform base
            u16* lb = Bs + (size_t)(wave * 256 + p * 64) * 8;
            gl2lds16(ga, la);
            gl2lds16(gb, lb);
        }
        __syncthreads();                    // drains vmcnt -> LDS valid
        #pragma unroll
        for (int ks = 0; ks < 2; ks++) {
            const int chsw = (((ks * 4 + q8) ^ (cc & 7)) * 8);
            bf16x8 af[4], bfr[4];
            #pragma unroll
            for (int mi = 0; mi < 4; mi++)
                af[mi] = *(const bf16x8*)(As + (wr * 64 + mi * 16 + cc) * 64 + chsw);
            #pragma unroll
            for (int ni = 0; ni < 4; ni++)
                bfr[ni] = *(const bf16x8*)(Bs + (wc * 64 + ni * 16 + cc) * 64 + chsw);
            #pragma unroll
            for (int mi = 0; mi < 4; mi++)
                #pragma unroll
                for (int ni = 0; ni < 4; ni++)
                    acc[mi][ni] = __builtin_amdgcn_mfma_f32_16x16x32_bf16(af[mi], bfr[ni], acc[mi][ni], 0, 0, 0);
        }
    }

    // repack through LDS, then coalesced 16B stores
    __syncthreads();                        // all fragment reads done; reuse smem as Ct
    #pragma unroll
    for (int mi = 0; mi < 4; mi++)
        #pragma unroll
        for (int r = 0; r < 4; r++) {
            int lr = wr * 64 + mi * 16 + q8 * 4 + r;
            #pragma unroll
            for (int ni = 0; ni < 4; ni++)
                smem[lr * CP + wc * 64 + ni * 16 + cc] = f2bf(acc[mi][ni][r]);
        }
    __syncthreads();

    if (mode == 2) {                        // V^T: rows are Vt rows, cols are s -> direct
        #pragma unroll
        for (int p = 0; p < 8; p++) {
            int id = p * 256 + tid;
            int row = id >> 4, c8 = (id & 15) * 8;
            uint4 val = *(const uint4*)(smem + row * CP + c8);
            *(uint4*)(VtOut + (size_t)(r0 + row) * VTP3 + c0 + c8) = val;
        }
        return;
    }

    #pragma unroll
    for (int p = 0; p < 8; p++) {
        int id = p * 256 + tid;             // 2048 uint4 chunks (128 rows x 16)
        int row = id >> 4, c8 = (id & 15) * 8;
        long grow = r0 + row;
        if (grow >= ((mode == 1) ? 8192 : NTOK)) continue;
        uint4 val = *(const uint4*)(smem + row * CP + c8);
        int b, n;
        if (mode == 1) { b = (int)(grow >> 10); n = (int)(grow & 1023) + 1; }
        else           { b = (int)(grow / NSEQ); n = (int)(grow % NSEQ); }
        int c2 = c0 + c8;                   // < 768 for both K and q grids
        u16* dst = (mode == 1) ? qOut : kOut;
        int d0 = c2 & 63;
        {
            u16 e[8];
            unsigned wv[4] = {val.x, val.y, val.z, val.w};
            #pragma unroll
            for (int j = 0; j < 4; j++) { e[2*j] = (u16)(wv[j] & 0xFFFFu); e[2*j+1] = (u16)(wv[j] >> 16); }
            bool doro = (d0 < 32) && (n >= 1);
            if (mode == 1 || doro) {
                float f[8];
                #pragma unroll
                for (int j = 0; j < 8; j++) f[j] = bf2f(e[j]);
                if (mode == 1) {
                    #pragma unroll
                    for (int j = 0; j < 8; j++) f[j] *= 0.125f;   // fold softmax scale into q (exact)
                }
                if (doro) {
                    int pos = n - 1;
                    const float* cp = cosb + pos * 32 + d0;
                    const float* sp = sinb + pos * 32 + d0;
                    float4 cv0 = *(const float4*)cp, cv1 = *(const float4*)(cp + 4);
                    float4 sv0 = *(const float4*)sp, sv1 = *(const float4*)(sp + 4);
                    float ca[8] = {cv0.x, cv0.y, cv0.z, cv0.w, cv1.x, cv1.y, cv1.z, cv1.w};
                    float sa[8] = {sv0.x, sv0.y, sv0.z, sv0.w, sv1.x, sv1.y, sv1.z, sv1.w};
                    #pragma unroll
                    for (int pr = 0; pr < 4; pr++) {
                        float a = f[2*pr], bb2 = f[2*pr+1];
                        f[2*pr]   = a   * ca[2*pr]   - bb2 * sa[2*pr];
                        f[2*pr+1] = bb2 * ca[2*pr+1] + a   * sa[2*pr+1];
                    }
                }
                #pragma unroll
                for (int j = 0; j < 8; j++) e[j] = f2bf(f[j]);
            }
            #pragma unroll
            for (int j = 0; j < 4; j++) wv[j] = (unsigned)e[2*j] | ((unsigned)e[2*j+1] << 16);
            val = make_uint4(wv[0], wv[1], wv[2], wv[3]);
        }
        *(uint4*)(dst + ((size_t)(b * NHEADS + (c2 >> 6)) * NSEQ + n) * DHEAD + (c2 & 63)) = val;
    }
}

// ---------------- output GEMM: fp32 d_out + bias ----------------
__launch_bounds__(256)
__global__ void gemm_out(const u16* __restrict__ A, const u16* __restrict__ Bn,
                         const float* __restrict__ bias, float* __restrict__ Of, int M)
{
    __shared__ u16 smem[16384];             // As+Bs 32KB
    u16* As = smem;
    u16* Bs = smem + 8192;
    const int tid  = threadIdx.x;
    const int wave = tid >> 6, lane = tid & 63;
    const int q8 = lane >> 4, cc = lane & 15;
    const int wr = wave >> 1, wc = wave & 1;
    const long r0 = (long)blockIdx.y * 128;
    const int  c0 = blockIdx.x * 128;

    f32x4 acc[4][4] = {};

    for (int k0 = 0; k0 < 768; k0 += 64) {
        __syncthreads();
        #pragma unroll
        for (int p = 0; p < 4; p++) {
            int chunk = wave * 256 + p * 64 + lane;
            int row = chunk >> 3, cs = chunk & 7;
            int src = cs ^ (row & 7);
            const u16* ga = A  + (size_t)(r0 + row) * 768 + k0 + src * 8;
            const u16* gb = Bn + (size_t)(c0 + row) * 768 + k0 + src * 8;
            u16* la = As + (size_t)(wave * 256 + p * 64) * 8;
            u16* lb = Bs + (size_t)(wave * 256 + p * 64) * 8;
            gl2lds16(ga, la);
            gl2lds16(gb, lb);
        }
        __syncthreads();
        #pragma unroll
        for (int ks = 0; ks < 2; ks++) {
            const int chsw = (((ks * 4 + q8) ^ (cc & 7)) * 8);
            bf16x8 af[4], bfr[4];
            #pragma unroll
            for (int mi = 0; mi < 4; mi++)
                af[mi] = *(const bf16x8*)(As + (wr * 64 + mi * 16 + cc) * 64 + chsw);
            #pragma unroll
            for (int ni = 0; ni < 4; ni++)
                bfr[ni] = *(const bf16x8*)(Bs + (wc * 64 + ni * 16 + cc) * 64 + chsw);
            #pragma unroll
            for (int mi = 0; mi < 4; mi++)
                #pragma unroll
                for (int ni = 0; ni < 4; ni++)
                    acc[mi][ni] = __builtin_amdgcn_mfma_f32_16x16x32_bf16(af[mi], bfr[ni], acc[mi][ni], 0, 0, 0);
        }
    }
    #pragma unroll
    for (int mi = 0; mi < 4; mi++) {
        #pragma unroll
        for (int r = 0; r < 4; r++) {
            long row = r0 + wr * 64 + mi * 16 + q8 * 4 + r;
            if (row >= M) continue;
            #pragma unroll
            for (int ni = 0; ni < 4; ni++) {
                int col = c0 + wc * 64 + ni * 16 + cc;
                Of[(size_t)row * 768 + col] = acc[mi][ni][r] + bias[col];
            }
        }
    }
}

// ---------------- flash attention: 512 thr, 8 waves x 16 rows, dbuf async K/V ----------
__launch_bounds__(512)
__global__ void attn_kernel(const u16* __restrict__ q, const u16* __restrict__ k,
                            const u16* __restrict__ Vt, u16* __restrict__ o)
{
    __shared__ u16 Kb[2][4096];
    __shared__ u16 Vb[2][4096];
    __shared__ u16 Ps[8 * 16 * LDP];  // per-wave 16-row P tile
    const int tid  = threadIdx.x;
    const int wave = tid >> 6, lane = tid & 63;
    const int q8 = lane >> 4, cc = lane & 15;
    const int bh = blockIdx.x;        // 96%8==0 -> all q-tiles of a head share an XCD
    const int i0 = blockIdx.y * 128;
    const int b = bh / NHEADS, h = bh % NHEADS;
    const size_t kbase = (size_t)bh * NSEQ * 64;
    const size_t vbase = (size_t)(h * 64) * VTP3 + (size_t)b * 1032;   // Vt col = b*1032+n

    // Q fragments: invariant across j-tiles -> registers, straight from global
    bf16x8 aq[2];
    {
        const u16* qp = q + kbase + (size_t)(i0 + wave * 16 + cc) * 64;
        aq[0] = *(const bf16x8*)(qp + q8 * 8);
        aq[1] = *(const bf16x8*)(qp + 32 + q8 * 8);
    }

    auto stage = [&](int jt, int buf) {
        int j0 = jt * 64;
        int chunk = wave * 64 + lane;       // 512 chunks per 64x64 tile
        int row = chunk >> 3, cs = chunk & 7;
        int src = cs ^ (row & 7);
        gl2lds16(k  + kbase + (size_t)(j0 + row) * 64 + src * 8, Kb[buf] + wave * 512);
        gl2lds16(Vt + vbase + (size_t)row * VTP3 + j0 + src * 8,  Vb[buf] + wave * 512);
    };

    stage(0, 0);
    f32x4 O[4] = {};
    float lsum[4] = {0.f, 0.f, 0.f, 0.f};
    u16* Psw = Ps + wave * 16 * LDP;

    for (int jt = 0; jt < 17; jt++) {
        __syncthreads();                   // drains async loads; all waves synced
        const u16* Kc = Kb[jt & 1];
        const u16* Vc = Vb[jt & 1];
        if (jt < 16) stage(jt + 1, (jt + 1) & 1);   // prefetch overlaps compute below

        // S = Q K^T
        f32x4 sf[4] = {};
        #pragma unroll
        for (int ks = 0; ks < 2; ks++) {
            #pragma unroll
            for (int ni = 0; ni < 4; ni++) {
                bf16x8 bk = *(const bf16x8*)(Kc + (ni * 16 + cc) * 64 + (((ks * 4 + q8) ^ (cc & 7)) * 8));
                sf[ni] = __builtin_amdgcn_mfma_f32_16x16x32_bf16(aq[ks], bk, sf[ni], 0, 0, 0);
            }
        }

        // max-free softmax (q pre-scaled): p = exp(s)
        bool mask = (jt == 16);
        #pragma unroll
        for (int ni = 0; ni < 4; ni++)
            #pragma unroll
            for (int r = 0; r < 4; r++) {
                float p = __expf(sf[ni][r]);
                if (mask && (ni * 16 + cc != 0)) p = 0.f;   // only j=1024 valid in tail tile
                lsum[r] += p;
                unsigned u; __builtin_memcpy(&u, &p, 4);
                Psw[(q8 * 4 + r) * LDP + ni * 16 + cc] = (u16)((u + 0x8000u) >> 16);
            }

        // O += P V
        #pragma unroll
        for (int ks = 0; ks < 2; ks++) {
            bf16x8 pa = *(const bf16x8*)(Psw + cc * LDP + ks * 32 + q8 * 8);
            #pragma unroll
            for (int ni = 0; ni < 4; ni++) {
                bf16x8 vb = *(const bf16x8*)(Vc + (ni * 16 + cc) * 64 + (((ks * 4 + q8) ^ (cc & 7)) * 8));
                O[ni] = __builtin_amdgcn_mfma_f32_16x16x32_bf16(pa, vb, O[ni], 0, 0, 0);
            }
        }
    }

    #pragma unroll
    for (int r = 0; r < 4; r++) {
        lsum[r] += __shfl_xor(lsum[r], 1, 64);
        lsum[r] += __shfl_xor(lsum[r], 2, 64);
        lsum[r] += __shfl_xor(lsum[r], 4, 64);
        lsum[r] += __shfl_xor(lsum[r], 8, 64);
    }
    #pragma unroll
    for (int r = 0; r < 4; r++) {
        int i = i0 + wave * 16 + q8 * 4 + r;
        if (i >= NSEQ) continue;
        float inv = 1.0f / lsum[r];
        #pragma unroll
        for (int ni = 0; ni < 4; ni++)
            o[((size_t)(b * NSEQ + i)) * 768 + h * 64 + ni * 16 + cc] = f2bf(O[ni][r] * inv);
    }
}

extern "C" void kernel_launch(void* const* d_in, const int* in_sizes, int n_in,
                              void* d_out, int out_size, void* d_ws, size_t ws_size,
                              hipStream_t stream)
{
    const float* x     = (const float*)d_in[0];
    const float* sinb  = (const float*)d_in[1];
    const float* cosb  = (const float*)d_in[2];
    const float* ln_g  = (const float*)d_in[3];
    const float* ln_b  = (const float*)d_in[4];
    const float* dw_w  = (const float*)d_in[5];
    const float* pw_w  = (const float*)d_in[6];
    const float* kv_w  = (const float*)d_in[7];
    const float* out_w = (const float*)d_in[8];
    const float* out_b = (const float*)d_in[9];
    (void)in_sizes; (void)n_in; (void)out_size; (void)ws_size;

    u16* ws = (u16*)d_ws;                      // offsets in ushort units
    u16* xn_bf    = ws;                        // 6,297,600 (reused as attn output)
    u16* dwout_bf = ws + 6297600;              // 6,291,456
    u16* q_bf     = ws + 12589056;             // 6,297,600
    u16* k_bf     = ws + 18886656;             // 6,297,600
    u16* Vt       = ws + 25184256;             // 6,389,760 (768 x 8320)
    u16* pw_bf    = ws + 31574016;             // 589,824
    u16* kv_wT    = ws + 32163840;             // 1,179,648
    u16* out_wT   = ws + 33343488;             // 589,824
    float* dwT    = (float*)(ws + 33933312);   // 19,200 fp32 -> total ~68 MB
    u16* attn_bf  = xn_bf;                     // xn dead after proj GEMM

    ln_pre_kernel <<<NTOK + 4107, 256, 0, stream>>>(x, ln_g, ln_b, xn_bf, q_bf,
                                                    dw_w, pw_w, kv_w, out_w,
                                                    dwT, pw_bf, kv_wT, out_wT);
    dw_kernel     <<<3072, 256, 0, stream>>>(xn_bf, dwT, dwout_bf);
    gemm_proj     <<<1164, 256, 0, stream>>>(xn_bf, dwout_bf, kv_wT, pw_bf,
                                             k_bf, Vt, q_bf, sinb, cosb);
    attn_kernel   <<<dim3(96, 9), 512, 0, stream>>>(q_bf, k_bf, Vt, attn_bf);
    gemm_out      <<<dim3(6, 65), 256, 0, stream>>>(attn_bf, out_wT, out_b, (float*)d_out, NTOK);
}